// Round 17
// baseline (186.790 us; speedup 1.0000x reference)
//
#include <hip/hip_runtime.h>
#include <hip/hip_bf16.h>
#include <math.h>

#define DIM      1024
#define D_STATE  64
#define D_CONV   4
#define N_HEADS  8
#define D_INNER  2048
#define HEAD_DIM 256
#define NPROJ    4232      // 2048 + 2048 + 8 + 64 + 64
#define BATCH    2
#define SEQ      1024
#define M_ROWS   (BATCH * SEQ)   // 2048
#define OFF_Z    0
#define OFF_XC   2048
#define OFF_DT   4096
#define OFF_B    4104
#define OFF_C    4168

#define CHUNK    64
#define N_CHUNK  (SEQ / CHUNK)    // 16
#define STATE_PER_BH (HEAD_DIM * D_STATE)   // 16384 elems

#define NPROJ_PAD 4352            // 34 * 128 (GEMM1 grid only; B rows guarded)
#define PADT 72                   // padded u16 row pitch for 64-wide LDS tiles

typedef unsigned short u16;
typedef unsigned int   u32;
typedef _Float16 f16x8 __attribute__((ext_vector_type(8)));
typedef float    f32x4 __attribute__((ext_vector_type(4)));
typedef unsigned short u16x8 __attribute__((ext_vector_type(8)));

__device__ __forceinline__ u16 f2h(float f) {
    _Float16 h = (_Float16)f;
    return __builtin_bit_cast(u16, h);
}
__device__ __forceinline__ float h2f(u16 u) {
    return (float)__builtin_bit_cast(_Float16, u);
}

__device__ __forceinline__ void load_lds16(const void* g, void* l) {
    __builtin_amdgcn_global_load_lds((const __attribute__((address_space(1))) unsigned int*)g,
                                     (__attribute__((address_space(3))) unsigned int*)l,
                                     16, 0, 0);
}

// fast softplus: __logf/__expf (v_exp/v_log based); error ~1e-6 abs, far
// below the fp16 noise floor of the scan path.
__device__ __forceinline__ float softplus_f(float v) {
    return (v > 20.f) ? v : __logf(1.f + __expf(v));
}

// ---------------------------------------------------------------------------
// merged cast: x -> fp16, in_proj_w -> fp16, out_proj_w*norm_w -> fp16.
// block 0 additionally zeroes rowSS (replaces a hipMemsetAsync dispatch).
// ---------------------------------------------------------------------------
__global__ __launch_bounds__(256) void cast3_kernel(
        const float* __restrict__ s0, u16* __restrict__ h0, int n0,
        const float* __restrict__ s1, u16* __restrict__ h1, int n1,
        const float* __restrict__ s2, const float* __restrict__ nw,
        u16* __restrict__ h2, int n2, float* __restrict__ rowSS) {
    if (blockIdx.x == 0) {
#pragma unroll
        for (int j = 0; j < 8; ++j)
            rowSS[threadIdx.x + j * 256] = 0.f;
    }
    int i4 = (blockIdx.x * 256 + threadIdx.x) * 4;
    if (i4 < n0) {
        float4 v = *(const float4*)&s0[i4];
        ushort4 h;
        h.x = f2h(v.x); h.y = f2h(v.y); h.z = f2h(v.z); h.w = f2h(v.w);
        *(ushort4*)&h0[i4] = h;
        return;
    }
    i4 -= n0;
    if (i4 < n1) {
        float4 v = *(const float4*)&s1[i4];
        ushort4 h;
        h.x = f2h(v.x); h.y = f2h(v.y); h.z = f2h(v.z); h.w = f2h(v.w);
        *(ushort4*)&h1[i4] = h;
        return;
    }
    i4 -= n1;
    if (i4 >= n2) return;
    float4 v = *(const float4*)&s2[i4];
    int c = i4 & (D_INNER - 1);
    ushort4 h;
    h.x = f2h(v.x * nw[c]);
    h.y = f2h(v.y * nw[c + 1]);
    h.z = f2h(v.z * nw[c + 2]);
    h.w = f2h(v.w * nw[c + 3]);
    *(ushort4*)&h2[i4] = h;
}

// ---------------------------------------------------------------------------
// fp16 MFMA GEMM: C = A @ B^T, fp32 accum (m97 structure + 2-step stage:
// two independent 32-wide K-tiles staged per barrier pair -> half the
// vmcnt(0)+s_barrier drains, bit-identical accumulation order).
// BM=128 x BN tile, 256 thr (2x2 waves).  Requires kPer % 64 == 0.
// F16OUT=true  (GEMM1): C stored fp16; dt cols [OFF_DT,OFF_DT+8) also fp32.
// F16OUT=false (GEMM2): fused epilogue — applies per-row RMS scale from
//   rowSS (complete before launch, stream-ordered) and atomicAdds into out
//   (harness zeroes out before launch; 2 z-slices accumulate; fp add of two
//   terms is order-independent).  Eliminates the reduce pass + 42MB traffic.
// BN=128 for GEMM1 (round-10 A/B: BN=64 gave +occupancy but -MfmaUtil, +13us).
// GEMM2: split-K=2 (round-15 A/B: split-K=4 regressed — partial traffic).
// ---------------------------------------------------------------------------
template<int BN, bool F16OUT>
__global__ __launch_bounds__(256) void gemm_mfma1(const u16* __restrict__ Ah,
                                                  const u16* __restrict__ Bh,
                                                  void* __restrict__ Cv,
                                                  float* __restrict__ dt32,
                                                  const float* __restrict__ rowSS,
                                                  int K, int ldc, int Nstore,
                                                  int NrowsB) {
    __shared__ u16 As0[128 * 32];
    __shared__ u16 As1[128 * 32];
    __shared__ u16 Bs0[BN * 32];
    __shared__ u16 Bs1[BN * 32];

    const int tid  = threadIdx.x;
    const int wave = tid >> 6;
    const int lane = tid & 63;
    const int fr   = lane & 15;
    const int kc   = lane >> 4;
    const int m0   = blockIdx.y * 128;
    const int n0   = blockIdx.x * BN;
    const int wm   = (wave & 1) * 64;
    const int wn   = (wave >> 1) * (BN / 2);

    const int kPer = K / gridDim.z;
    const int kBeg = blockIdx.z * kPer;

    f32x4 acc[4][BN / 32];
#pragma unroll
    for (int i = 0; i < 4; ++i)
#pragma unroll
        for (int j = 0; j < BN / 32; ++j) acc[i][j] = (f32x4)0.f;

    for (int k0 = kBeg; k0 < kBeg + kPer; k0 += 64) {
        __syncthreads();
#pragma unroll
        for (int q = 0; q < 2; ++q) {
            int s = wave * 128 + q * 64 + lane;
            int r = s >> 2, pc = s & 3;
            int gc = pc ^ ((r >> 1) & 3);
            size_t goff = (size_t)(m0 + r) * K + k0 + gc * 8;
            load_lds16(Ah + goff,      &As0[(wave * 128 + q * 64) * 8]);
            load_lds16(Ah + goff + 32, &As1[(wave * 128 + q * 64) * 8]);
        }
#pragma unroll
        for (int q = 0; q < BN / 64; ++q) {
            int s = wave * BN + q * 64 + lane;
            int r = s >> 2, pc = s & 3;
            int gc = pc ^ ((r >> 1) & 3);
            if (n0 + r < NrowsB) {   // OOB rows: stale LDS, results never stored
                size_t goff = (size_t)(n0 + r) * K + k0 + gc * 8;
                load_lds16(Bh + goff,      &Bs0[(wave * BN + q * 64) * 8]);
                load_lds16(Bh + goff + 32, &Bs1[(wave * BN + q * 64) * 8]);
            }
        }
        __syncthreads();

        // ---- sub-step 0 (cols k0..k0+31) ----
        {
            f16x8 af[4];
#pragma unroll
            for (int i = 0; i < 4; ++i) {
                int r = wm + i * 16 + fr;
                int off = r * 32 + (kc ^ ((r >> 1) & 3)) * 8;
                af[i] = *(const f16x8*)&As0[off];
            }
            f16x8 bf[BN / 32];
#pragma unroll
            for (int j = 0; j < BN / 32; ++j) {
                int r = wn + j * 16 + fr;
                int off = r * 32 + (kc ^ ((r >> 1) & 3)) * 8;
                bf[j] = *(const f16x8*)&Bs0[off];
            }
#pragma unroll
            for (int i = 0; i < 4; ++i)
#pragma unroll
                for (int j = 0; j < BN / 32; ++j)
                    acc[i][j] = __builtin_amdgcn_mfma_f32_16x16x32_f16(af[i], bf[j], acc[i][j], 0, 0, 0);
        }
        // ---- sub-step 1 (cols k0+32..k0+63) ----
        {
            f16x8 af[4];
#pragma unroll
            for (int i = 0; i < 4; ++i) {
                int r = wm + i * 16 + fr;
                int off = r * 32 + (kc ^ ((r >> 1) & 3)) * 8;
                af[i] = *(const f16x8*)&As1[off];
            }
            f16x8 bf[BN / 32];
#pragma unroll
            for (int j = 0; j < BN / 32; ++j) {
                int r = wn + j * 16 + fr;
                int off = r * 32 + (kc ^ ((r >> 1) & 3)) * 8;
                bf[j] = *(const f16x8*)&Bs1[off];
            }
#pragma unroll
            for (int i = 0; i < 4; ++i)
#pragma unroll
                for (int j = 0; j < BN / 32; ++j)
                    acc[i][j] = __builtin_amdgcn_mfma_f32_16x16x32_f16(af[i], bf[j], acc[i][j], 0, 0, 0);
        }
    }

    // epilogue: C/D layout col=lane&15, row=(lane>>4)*4+reg  [m89/m91]
    const int row0 = m0 + wm + (lane >> 4) * 4;
    const int colb = n0 + wn + fr;
#pragma unroll
    for (int i = 0; i < 4; ++i)
#pragma unroll
        for (int j = 0; j < BN / 32; ++j) {
            int col = colb + j * 16;
            if (col < Nstore) {
#pragma unroll
                for (int t = 0; t < 4; ++t) {
                    int row = row0 + i * 16 + t;
                    float v = acc[i][j][t];
                    if constexpr (F16OUT) {
                        ((u16*)Cv)[(size_t)row * ldc + col] = f2h(v);
                        if ((unsigned)(col - OFF_DT) < 8u)
                            dt32[(size_t)row * 8 + (col - OFF_DT)] = v;
                    } else {
                        float scale = rsqrtf(rowSS[row] * (1.f / (float)D_INNER) + 1e-6f);
                        atomicAdd(&((float*)Cv)[(size_t)row * ldc + col], v * scale);
                    }
                }
            }
        }
}

// ---------------------------------------------------------------------------
// depthwise causal conv (k=4) + SiLU -> xh (fp16); vectorized u16x8 (G13).
// ---------------------------------------------------------------------------
__global__ __launch_bounds__(256) void conv_silu_kernel(const u16* __restrict__ zxh,
                                                        const float* __restrict__ conv_w,
                                                        const float* __restrict__ conv_b,
                                                        u16* __restrict__ xh) {
    int idx8 = blockIdx.x * 256 + threadIdx.x;   // 0 .. M_ROWS*D_INNER/8-1
    int c0 = (idx8 & 255) * 8;
    int m  = idx8 >> 8;
    int l  = m & (SEQ - 1);

    f32x4 wv[8];
#pragma unroll
    for (int j = 0; j < 8; ++j) wv[j] = *(const f32x4*)&conv_w[(c0 + j) * 4];
    float acc[8];
#pragma unroll
    for (int j = 0; j < 8; ++j) acc[j] = conv_b[c0 + j];
#pragma unroll
    for (int k = 0; k < D_CONV; ++k) {
        int lj = l + k - (D_CONV - 1);
        if (lj >= 0) {
            u16x8 v = *(const u16x8*)&zxh[(size_t)(m + k - (D_CONV - 1)) * NPROJ + OFF_XC + c0];
#pragma unroll
            for (int j = 0; j < 8; ++j)
                acc[j] = fmaf(h2f(v[j]), wv[j][k], acc[j]);
        }
    }
    u16x8 o;
#pragma unroll
    for (int j = 0; j < 8; ++j) o[j] = f2h(acc[j] / (1.f + __expf(-acc[j])));
    *(u16x8*)&xh[(size_t)m * D_INNER + c0] = o;
}

// ---------------------------------------------------------------------------
// PASS 1 (states only): per (b,h,chunk,dq): S_c = (w2*B)^T @ X  -> Sloc (fp16).
// dq==0 block also writes csum[bh][c] = sum of dt over the chunk (SD63).
// Staging vectorized: u16x8 loads (16B), one w2 exp per 8-wide chunk.
// ---------------------------------------------------------------------------
__global__ __launch_bounds__(256) void scan_state_mfma(const u16* __restrict__ zxh,
                                                       const float* __restrict__ dt32,
                                                       const u16* __restrict__ xh,
                                                       const float* __restrict__ dt_bias,
                                                       const float* __restrict__ A_log,
                                                       u16* __restrict__ Sloc,
                                                       float* __restrict__ csum) {
    const int blk = blockIdx.x;                 // 0..1023
    const int dq = blk & 3;
    const int c  = (blk >> 2) & (N_CHUNK - 1);
    const int bh = blk >> 6;
    const int hh = bh & (N_HEADS - 1);
    const int b  = bh >> 3;
    const int t    = threadIdx.x;
    const int wave = t >> 6;
    const int lane = t & 63;
    const int fr   = lane & 15;
    const int quad = lane >> 4;

    __shared__ float SDs[64];
    __shared__ u16 BwT[64 * PADT];
    __shared__ u16 XsT[64 * PADT];

    const int m0   = b * SEQ + c * CHUNK;
    const int xcol = hh * HEAD_DIM + dq * 64;
    const float Ahd = -__expf(A_log[hh]);
    const float dtb = dt_bias[hh];

    if (t < 64) {
        float d = softplus_f(dt32[(size_t)(m0 + t) * 8 + hh] + dtb);
#pragma unroll
        for (int off = 1; off < 64; off <<= 1) {
            float o = __shfl_up(d, off);
            if (lane >= off) d += o;
        }
        SDs[t] = d;
    }
    __syncthreads();
    const float SD63 = SDs[63];
    if (dq == 0 && t == 0) csum[bh * N_CHUNK + c] = SD63;

#pragma unroll
    for (int i = 0; i < 2; ++i) {
        int ch = t + i * 256;                 // 0..511 = 64 rows x 8 chunks
        int r = ch >> 3, n0 = (ch & 7) * 8;
        u16x8 bv8 = *(const u16x8*)&zxh[(size_t)(m0 + r) * NPROJ + OFF_B + n0];
        u16x8 xv8 = *(const u16x8*)&xh[(size_t)(m0 + r) * D_INNER + xcol + n0];
        float w2 = __expf(Ahd * (SD63 - SDs[r]));
#pragma unroll
        for (int j = 0; j < 8; ++j) {
            BwT[(n0 + j) * PADT + r] = f2h(h2f(bv8[j]) * w2);
            XsT[(n0 + j) * PADT + r] = xv8[j];
        }
    }
    __syncthreads();

    const int tm0 = wave * 16;
    f32x4 sa[4];
#pragma unroll
    for (int j = 0; j < 4; ++j) sa[j] = (f32x4)0.f;
    __builtin_amdgcn_s_setprio(1);
#pragma unroll
    for (int kk = 0; kk < 2; ++kk) {
        f16x8 af = *(const f16x8*)&BwT[(tm0 + fr) * PADT + kk * 32 + quad * 8];
#pragma unroll
        for (int j = 0; j < 4; ++j) {
            f16x8 bf = *(const f16x8*)&XsT[(j * 16 + fr) * PADT + kk * 32 + quad * 8];
            sa[j] = __builtin_amdgcn_mfma_f32_16x16x32_f16(af, bf, sa[j], 0, 0, 0);
        }
    }
    __builtin_amdgcn_s_setprio(0);
    size_t sbase = (size_t)(bh * N_CHUNK + c) * STATE_PER_BH;
#pragma unroll
    for (int j = 0; j < 4; ++j)
#pragma unroll
        for (int reg = 0; reg < 4; ++reg) {
            int nn = tm0 + quad * 4 + reg;
            int dd = j * 16 + fr;
            Sloc[sbase + (size_t)nn * HEAD_DIM + dq * 64 + dd] = f2h(sa[j][reg]);
        }
}

// ---------------------------------------------------------------------------
// PASS 2: inter-chunk recurrence in place on fp16 Sloc (u32 = 2 packed fp16).
// ---------------------------------------------------------------------------
__global__ __launch_bounds__(256) void scan_combine2(const float* __restrict__ csum,
                                                     const float* __restrict__ A_log,
                                                     u32* __restrict__ Sl) {
    const int blk = blockIdx.x;               // 0..511
    const int seg = blk & 31;                 // 32 segs x 256 u32 = 8192 u32/chunk
    const int bh  = blk >> 5;
    const int hh  = bh & (N_HEADS - 1);
    const int t   = threadIdx.x;

    __shared__ float PS[N_CHUNK];
    if (t < N_CHUNK) {
        float Ahd = -__expf(A_log[hh]);
        PS[t] = __expf(Ahd * csum[bh * N_CHUNK + t]);
    }
    __syncthreads();

    const int HPC = STATE_PER_BH / 2;         // 8192 u32 per chunk
    size_t base = (size_t)bh * N_CHUNK * HPC + seg * 256 + t;
    u32 Sv[N_CHUNK];
#pragma unroll
    for (int c = 0; c < N_CHUNK; ++c)
        Sv[c] = Sl[base + (size_t)c * HPC];
    float H0 = 0.f, H1 = 0.f;
#pragma unroll
    for (int c = 0; c < N_CHUNK; ++c) {
        Sl[base + (size_t)c * HPC] = ((u32)f2h(H1) << 16) | (u32)f2h(H0);
        float P = PS[c];
        H0 = fmaf(P, H0, h2f((u16)(Sv[c] & 0xffffu)));
        H1 = fmaf(P, H1, h2f((u16)(Sv[c] >> 16)));
    }
}

// ---------------------------------------------------------------------------
// PASS 3 (fused): per (b,h,chunk,dq):
//   G = C@B^T; P = mask*decay*G; Y = P@X + cum*(C@H) + D*x;
//   ybf = fp16(Y * silu(z)); rowSS += per-row sum of squares (atomic).
// 2 barriers: staging (incl Hdn) | G | alias-guard | Ps (same-wave) | PV.
// Ps aliases Bt. 37.2 KB -> 4 blocks/CU.
// ---------------------------------------------------------------------------
__global__ __launch_bounds__(256) void scan_ycorr_mfma(const u16* __restrict__ zxh,
                                                       const float* __restrict__ dt32,
                                                       const u16* __restrict__ xh,
                                                       const float* __restrict__ dt_bias,
                                                       const float* __restrict__ A_log,
                                                       const float* __restrict__ Dp,
                                                       const u16* __restrict__ Hini,
                                                       u16* __restrict__ ybf,
                                                       float* __restrict__ rowSS) {
    const int blk = blockIdx.x;                 // 0..1023
    const int dq = blk & 3;
    const int c  = (blk >> 2) & (N_CHUNK - 1);
    const int bh = blk >> 6;
    const int hh = bh & (N_HEADS - 1);
    const int b  = bh >> 3;
    const int t    = threadIdx.x;
    const int wave = t >> 6;
    const int lane = t & 63;
    const int fr   = lane & 15;
    const int quad = lane >> 4;

    __shared__ float SDs[64];
    __shared__ u16 Ct  [64 * PADT];
    __shared__ u16 BtPs[64 * PADT];             // Bt during G-phase, Ps after
    __shared__ u16 XsT [64 * PADT];
    __shared__ u16 Hdn [64 * PADT];

    const int m0   = b * SEQ + c * CHUNK;
    const int xcol = hh * HEAD_DIM + dq * 64;
    const float Ahd = -__expf(A_log[hh]);
    const float dtb = dt_bias[hh];

    if (t < 64) {
        float d = softplus_f(dt32[(size_t)(m0 + t) * 8 + hh] + dtb);
#pragma unroll
        for (int off = 1; off < 64; off <<= 1) {
            float o = __shfl_up(d, off);
            if (lane >= off) d += o;
        }
        SDs[t] = d;
    }

    // issue H loads first (they return while B/C/X staging proceeds)
    const int hr0 = t >> 3, hn0 = (t & 7) * 8;  // row/col chunks for H and X
    size_t hbase = (size_t)(bh * N_CHUNK + c) * STATE_PER_BH;
    u16x8 hreg0 = *(const u16x8*)&Hini[hbase + (size_t)hr0 * HEAD_DIM + dq * 64 + hn0];
    u16x8 hreg1 = *(const u16x8*)&Hini[hbase + (size_t)(hr0 + 32) * HEAD_DIM + dq * 64 + hn0];

    // B|C staging: 128 contiguous cols (4104..4231), 1024 u16x8 chunks
#pragma unroll
    for (int i = 0; i < 4; ++i) {
        int ch = t + i * 256;                  // 0..1023
        int r = ch >> 4, q = ch & 15;
        u16x8 v = *(const u16x8*)&zxh[(size_t)(m0 + r) * NPROJ + OFF_B + q * 8];
        if (q < 8) *(u16x8*)&BtPs[r * PADT + q * 8] = v;
        else       *(u16x8*)&Ct[r * PADT + (q - 8) * 8] = v;
    }
    // X staging: transposed
#pragma unroll
    for (int i = 0; i < 2; ++i) {
        int ch = t + i * 256;                  // 0..511
        int r = ch >> 3, n0 = (ch & 7) * 8;
        u16x8 xv8 = *(const u16x8*)&xh[(size_t)(m0 + r) * D_INNER + xcol + n0];
#pragma unroll
        for (int j = 0; j < 8; ++j)
            XsT[(n0 + j) * PADT + r] = xv8[j];
    }
    // Hdn staging (transposed) — loads were issued first, minimal stall
#pragma unroll
    for (int j = 0; j < 8; ++j) {
        Hdn[(hn0 + j) * PADT + hr0]      = hreg0[j];
        Hdn[(hn0 + j) * PADT + hr0 + 32] = hreg1[j];
    }
    __syncthreads();

    const int tm0 = wave * 16;

    // G = C@B^T
    f32x4 g[4];
#pragma unroll
    for (int j = 0; j < 4; ++j) g[j] = (f32x4)0.f;
    __builtin_amdgcn_s_setprio(1);
#pragma unroll
    for (int kk = 0; kk < 2; ++kk) {
        f16x8 af = *(const f16x8*)&Ct[(tm0 + fr) * PADT + kk * 32 + quad * 8];
#pragma unroll
        for (int j = 0; j < 4; ++j) {
            f16x8 bf = *(const f16x8*)&BtPs[(j * 16 + fr) * PADT + kk * 32 + quad * 8];
            g[j] = __builtin_amdgcn_mfma_f32_16x16x32_f16(af, bf, g[j], 0, 0, 0);
        }
    }
    __builtin_amdgcn_s_setprio(0);
    __syncthreads();                            // all waves done reading Bt

    // mask + decay -> Ps (into Bt's storage; same-wave rows only)
    {
        int trow = tm0 + quad * 4;
#pragma unroll
        for (int j = 0; j < 4; ++j) {
#pragma unroll
            for (int reg = 0; reg < 4; ++reg) {
                int tt = trow + reg, ss = j * 16 + fr;
                float val = 0.f;
                if (ss <= tt) val = __expf(Ahd * (SDs[tt] - SDs[ss])) * g[j][reg];
                BtPs[tt * PADT + ss] = f2h(val);
            }
        }
    }

    // Y1 = P @ X ; Y2 = C @ H   (no barrier: Ps is same-wave; Hdn/XsT staged)
    f32x4 ya[4], yb[4];
#pragma unroll
    for (int j = 0; j < 4; ++j) { ya[j] = (f32x4)0.f; yb[j] = (f32x4)0.f; }
    __builtin_amdgcn_s_setprio(1);
#pragma unroll
    for (int kk = 0; kk < 2; ++kk) {
        f16x8 afp = *(const f16x8*)&BtPs[(tm0 + fr) * PADT + kk * 32 + quad * 8];
        f16x8 afc = *(const f16x8*)&Ct[(tm0 + fr) * PADT + kk * 32 + quad * 8];
#pragma unroll
        for (int j = 0; j < 4; ++j) {
            f16x8 bx = *(const f16x8*)&XsT[(j * 16 + fr) * PADT + kk * 32 + quad * 8];
            f16x8 bh_ = *(const f16x8*)&Hdn[(j * 16 + fr) * PADT + kk * 32 + quad * 8];
            ya[j] = __builtin_amdgcn_mfma_f32_16x16x32_f16(afp, bx, ya[j], 0, 0, 0);
            yb[j] = __builtin_amdgcn_mfma_f32_16x16x32_f16(afc, bh_, yb[j], 0, 0, 0);
        }
    }
    __builtin_amdgcn_s_setprio(0);

    // epilogue: gate + fp16 store + row sum-of-squares
    const float Dh = Dp[hh];
#pragma unroll
    for (int reg = 0; reg < 4; ++reg) {
        int tt = tm0 + quad * 4 + reg;
        float cum = __expf(Ahd * SDs[tt]);
        size_t rowz = (size_t)(m0 + tt) * NPROJ;
        size_t rowy = (size_t)(m0 + tt) * D_INNER + xcol;
        float ss = 0.f;
#pragma unroll
        for (int j = 0; j < 4; ++j) {
            int dd = j * 16 + fr;
            float xv = h2f(XsT[dd * PADT + tt]);
            float z  = h2f(zxh[rowz + OFF_Z + xcol + dd]);
            float yv = ya[j][reg] + cum * yb[j][reg] + Dh * xv;
            float gated = yv * (z / (1.f + __expf(-z)));
            ybf[rowy + dd] = f2h(gated);
            ss += gated * gated;
        }
        // reduce across the 16 lanes of this quad (fr dimension)
#pragma unroll
        for (int off = 1; off < 16; off <<= 1) ss += __shfl_xor(ss, off);
        if (fr == 0) atomicAdd(&rowSS[m0 + tt], ss);
    }
}

// ---------------------------------------------------------------------------
extern "C" void kernel_launch(void* const* d_in, const int* in_sizes, int n_in,
                              void* d_out, int out_size, void* d_ws, size_t ws_size,
                              hipStream_t stream) {
    const float* x         = (const float*)d_in[0];
    const float* in_proj_w = (const float*)d_in[1];
    const float* conv_w    = (const float*)d_in[2];
    const float* conv_b    = (const float*)d_in[3];
    const float* A_log     = (const float*)d_in[4];
    const float* D_param   = (const float*)d_in[5];
    const float* dt_bias   = (const float*)d_in[6];
    const float* norm_w    = (const float*)d_in[7];
    const float* out_proj_w= (const float*)d_in[8];
    float* out = (float*)d_out;

    // workspace layout (floats):
    //  zx  @0         8,667,136  | zxh(u16, 17.3MB)
    //  R1  @8667136   2,166,784  | xh(u16)
    //  R2  @10833920  4,194,304  | lower half: xbf_h(u16) -> ybf(u16)
    //                            | upper half (@+2097152): wobf_h(u16)
    //  ab  @15028224     16,384  | csum(256) + rowSS(2048)
    //  R3  @15044608  4,194,304  | wibf_h(u16) -> Sloc(fp16) | dts fp32 side-buf
    float* ws  = (float*)d_ws;
    float* zx  = ws;
    float* R1  = zx + 8667136;
    float* R2  = R1 + 2166784;
    float* ab  = R2 + 4194304;
    float* R3  = ab + 16384;

    u16*  zxh    = (u16*)zx;                 // fp16 zxBCdt, 2048 x 4232
    u16*  xh     = (u16*)R1;
    u16*  xbf_h  = (u16*)R2;
    u16*  ybf    = (u16*)R2;                 // reuses xbf region after GEMM1
    u16*  wobf_h = (u16*)(R2 + 2097152);     // disjoint from xbf/ybf for all time
    float* csum  = ab;
    float* rowSS = ab + 2048;                // M_ROWS floats, atomic-accumulated
    u16*  wibf_h = (u16*)R3;
    u16*  Sloc   = (u16*)R3;                 // fp16 states; reuses wibf after GEMM1
    float* dts   = R3 + 2166784;             // fp32 dt side-buffer [M_ROWS][8]

    // 0) merged casts: x, in_proj_w, out_proj_w*norm_w (+ rowSS zeroing)
    {
        int n0 = M_ROWS * DIM;              // 2,097,152
        int n1 = NPROJ * DIM;               // 4,333,568
        int n2 = DIM * D_INNER;             // 2,097,152
        cast3_kernel<<<(n0 + n1 + n2) / 1024, 256, 0, stream>>>(
            x, xbf_h, n0, in_proj_w, wibf_h, n1, out_proj_w, norm_w, wobf_h, n2,
            rowSS);
    }

    // 1) zxBCdt = x @ in_proj_w^T  (2048 x 4232, K=1024), BN=128, fp16 out
    gemm_mfma1<128, true><<<dim3(NPROJ_PAD / 128, M_ROWS / 128, 1), 256, 0, stream>>>(
        xbf_h, wibf_h, zxh, dts, nullptr, DIM, NPROJ, NPROJ, NPROJ);

    // 2) conv + silu -> xh (fp16), vectorized u16x8
    conv_silu_kernel<<<(M_ROWS * D_INNER) / (256 * 8), 256, 0, stream>>>(
        zxh, conv_w, conv_b, xh);

    // 3) SSD chunked scan (fp16 states)
    scan_state_mfma<<<BATCH * N_HEADS * N_CHUNK * 4, 256, 0, stream>>>(
        zxh, dts, xh, dt_bias, A_log, Sloc, csum);
    scan_combine2<<<BATCH * N_HEADS * 32, 256, 0, stream>>>(
        csum, A_log, (u32*)Sloc);
    scan_ycorr_mfma<<<BATCH * N_HEADS * N_CHUNK * 4, 256, 0, stream>>>(
        zxh, dts, xh, dt_bias, A_log, D_param, Sloc, ybf, rowSS);

    // 4) out += (y_gated @ (W*nw)^T) * rms_scale  — split-K=2, fused epilogue
    //    (out zeroed by harness before launch; 2 z-slices atomicAdd)
    gemm_mfma1<64, false><<<dim3(DIM / 64, M_ROWS / 128, 2), 256, 0, stream>>>(
        ybf, wobf_h, out, nullptr, rowSS, D_INNER, DIM, DIM, DIM);
}

// Round 18
// 182.772 us; speedup vs baseline: 1.0220x; 1.0220x over previous
//
#include <hip/hip_runtime.h>
#include <hip/hip_bf16.h>
#include <math.h>

#define DIM      1024
#define D_STATE  64
#define D_CONV   4
#define N_HEADS  8
#define D_INNER  2048
#define HEAD_DIM 256
#define NPROJ    4232      // 2048 + 2048 + 8 + 64 + 64
#define BATCH    2
#define SEQ      1024
#define M_ROWS   (BATCH * SEQ)   // 2048
#define OFF_Z    0
#define OFF_XC   2048
#define OFF_DT   4096
#define OFF_B    4104
#define OFF_C    4168

#define CHUNK    64
#define N_CHUNK  (SEQ / CHUNK)    // 16
#define STATE_PER_BH (HEAD_DIM * D_STATE)   // 16384 elems

#define NPROJ_PAD 4352            // 34 * 128 (GEMM1 grid only; B rows guarded)
#define PADT 72                   // padded u16 row pitch for 64-wide LDS tiles

typedef unsigned short u16;
typedef unsigned int   u32;
typedef _Float16 f16x8 __attribute__((ext_vector_type(8)));
typedef float    f32x4 __attribute__((ext_vector_type(4)));
typedef unsigned short u16x8 __attribute__((ext_vector_type(8)));

__device__ __forceinline__ u16 f2h(float f) {
    _Float16 h = (_Float16)f;
    return __builtin_bit_cast(u16, h);
}
__device__ __forceinline__ float h2f(u16 u) {
    return (float)__builtin_bit_cast(_Float16, u);
}

__device__ __forceinline__ void load_lds16(const void* g, void* l) {
    __builtin_amdgcn_global_load_lds((const __attribute__((address_space(1))) unsigned int*)g,
                                     (__attribute__((address_space(3))) unsigned int*)l,
                                     16, 0, 0);
}

// fast softplus: __logf/__expf (v_exp/v_log based); error ~1e-6 abs, far
// below the fp16 noise floor of the scan path.
__device__ __forceinline__ float softplus_f(float v) {
    return (v > 20.f) ? v : __logf(1.f + __expf(v));
}

// ---------------------------------------------------------------------------
// merged cast: x -> fp16, in_proj_w -> fp16, out_proj_w*norm_w -> fp16.
// block 0 additionally zeroes rowSS (replaces a hipMemsetAsync dispatch).
// ---------------------------------------------------------------------------
__global__ __launch_bounds__(256) void cast3_kernel(
        const float* __restrict__ s0, u16* __restrict__ h0, int n0,
        const float* __restrict__ s1, u16* __restrict__ h1, int n1,
        const float* __restrict__ s2, const float* __restrict__ nw,
        u16* __restrict__ h2, int n2, float* __restrict__ rowSS) {
    if (blockIdx.x == 0) {
#pragma unroll
        for (int j = 0; j < 8; ++j)
            rowSS[threadIdx.x + j * 256] = 0.f;
    }
    int i4 = (blockIdx.x * 256 + threadIdx.x) * 4;
    if (i4 < n0) {
        float4 v = *(const float4*)&s0[i4];
        ushort4 h;
        h.x = f2h(v.x); h.y = f2h(v.y); h.z = f2h(v.z); h.w = f2h(v.w);
        *(ushort4*)&h0[i4] = h;
        return;
    }
    i4 -= n0;
    if (i4 < n1) {
        float4 v = *(const float4*)&s1[i4];
        ushort4 h;
        h.x = f2h(v.x); h.y = f2h(v.y); h.z = f2h(v.z); h.w = f2h(v.w);
        *(ushort4*)&h1[i4] = h;
        return;
    }
    i4 -= n1;
    if (i4 >= n2) return;
    float4 v = *(const float4*)&s2[i4];
    int c = i4 & (D_INNER - 1);
    ushort4 h;
    h.x = f2h(v.x * nw[c]);
    h.y = f2h(v.y * nw[c + 1]);
    h.z = f2h(v.z * nw[c + 2]);
    h.w = f2h(v.w * nw[c + 3]);
    *(ushort4*)&h2[i4] = h;
}

// ---------------------------------------------------------------------------
// fp16 MFMA GEMM: C = A @ B^T, fp32 accum (m97 structure + 2-step stage:
// two independent 32-wide K-tiles staged per barrier pair -> half the
// vmcnt(0)+s_barrier drains, bit-identical accumulation order).
// BM=128 x BN tile, 256 thr (2x2 waves).  Requires kPer % 64 == 0.
// F16OUT: C stored as fp16; dt columns [OFF_DT,OFF_DT+8) also stored fp32.
// BN=128 for GEMM1 (round-10 A/B: BN=64 gave +occupancy but -MfmaUtil, +13us).
// GEMM2: split-K=2 (round-15 A/B: split-K=4 regressed; round-17 A/B: fused
// atomic epilogue regressed +2.8us — separate reduce pass is fastest).
// ---------------------------------------------------------------------------
template<int BN, bool F16OUT>
__global__ __launch_bounds__(256) void gemm_mfma1(const u16* __restrict__ Ah,
                                                  const u16* __restrict__ Bh,
                                                  void* __restrict__ Cv,
                                                  float* __restrict__ dt32,
                                                  int K, int ldc, int Nstore,
                                                  int NrowsB, size_t zstride) {
    __shared__ u16 As0[128 * 32];
    __shared__ u16 As1[128 * 32];
    __shared__ u16 Bs0[BN * 32];
    __shared__ u16 Bs1[BN * 32];

    const int tid  = threadIdx.x;
    const int wave = tid >> 6;
    const int lane = tid & 63;
    const int fr   = lane & 15;
    const int kc   = lane >> 4;
    const int m0   = blockIdx.y * 128;
    const int n0   = blockIdx.x * BN;
    const int wm   = (wave & 1) * 64;
    const int wn   = (wave >> 1) * (BN / 2);

    const int kPer = K / gridDim.z;
    const int kBeg = blockIdx.z * kPer;
    const size_t zoff = (size_t)blockIdx.z * zstride;

    f32x4 acc[4][BN / 32];
#pragma unroll
    for (int i = 0; i < 4; ++i)
#pragma unroll
        for (int j = 0; j < BN / 32; ++j) acc[i][j] = (f32x4)0.f;

    for (int k0 = kBeg; k0 < kBeg + kPer; k0 += 64) {
        __syncthreads();
#pragma unroll
        for (int q = 0; q < 2; ++q) {
            int s = wave * 128 + q * 64 + lane;
            int r = s >> 2, pc = s & 3;
            int gc = pc ^ ((r >> 1) & 3);
            size_t goff = (size_t)(m0 + r) * K + k0 + gc * 8;
            load_lds16(Ah + goff,      &As0[(wave * 128 + q * 64) * 8]);
            load_lds16(Ah + goff + 32, &As1[(wave * 128 + q * 64) * 8]);
        }
#pragma unroll
        for (int q = 0; q < BN / 64; ++q) {
            int s = wave * BN + q * 64 + lane;
            int r = s >> 2, pc = s & 3;
            int gc = pc ^ ((r >> 1) & 3);
            if (n0 + r < NrowsB) {   // OOB rows: stale LDS, results never stored
                size_t goff = (size_t)(n0 + r) * K + k0 + gc * 8;
                load_lds16(Bh + goff,      &Bs0[(wave * BN + q * 64) * 8]);
                load_lds16(Bh + goff + 32, &Bs1[(wave * BN + q * 64) * 8]);
            }
        }
        __syncthreads();

        // ---- sub-step 0 (cols k0..k0+31) ----
        {
            f16x8 af[4];
#pragma unroll
            for (int i = 0; i < 4; ++i) {
                int r = wm + i * 16 + fr;
                int off = r * 32 + (kc ^ ((r >> 1) & 3)) * 8;
                af[i] = *(const f16x8*)&As0[off];
            }
            f16x8 bf[BN / 32];
#pragma unroll
            for (int j = 0; j < BN / 32; ++j) {
                int r = wn + j * 16 + fr;
                int off = r * 32 + (kc ^ ((r >> 1) & 3)) * 8;
                bf[j] = *(const f16x8*)&Bs0[off];
            }
#pragma unroll
            for (int i = 0; i < 4; ++i)
#pragma unroll
                for (int j = 0; j < BN / 32; ++j)
                    acc[i][j] = __builtin_amdgcn_mfma_f32_16x16x32_f16(af[i], bf[j], acc[i][j], 0, 0, 0);
        }
        // ---- sub-step 1 (cols k0+32..k0+63) ----
        {
            f16x8 af[4];
#pragma unroll
            for (int i = 0; i < 4; ++i) {
                int r = wm + i * 16 + fr;
                int off = r * 32 + (kc ^ ((r >> 1) & 3)) * 8;
                af[i] = *(const f16x8*)&As1[off];
            }
            f16x8 bf[BN / 32];
#pragma unroll
            for (int j = 0; j < BN / 32; ++j) {
                int r = wn + j * 16 + fr;
                int off = r * 32 + (kc ^ ((r >> 1) & 3)) * 8;
                bf[j] = *(const f16x8*)&Bs1[off];
            }
#pragma unroll
            for (int i = 0; i < 4; ++i)
#pragma unroll
                for (int j = 0; j < BN / 32; ++j)
                    acc[i][j] = __builtin_amdgcn_mfma_f32_16x16x32_f16(af[i], bf[j], acc[i][j], 0, 0, 0);
        }
    }

    // epilogue: C/D layout col=lane&15, row=(lane>>4)*4+reg  [m89/m91]
    const int row0 = m0 + wm + (lane >> 4) * 4;
    const int colb = n0 + wn + fr;
#pragma unroll
    for (int i = 0; i < 4; ++i)
#pragma unroll
        for (int j = 0; j < BN / 32; ++j) {
            int col = colb + j * 16;
            if (col < Nstore) {
#pragma unroll
                for (int t = 0; t < 4; ++t) {
                    int row = row0 + i * 16 + t;
                    float v = acc[i][j][t];
                    if constexpr (F16OUT) {
                        ((u16*)Cv)[(size_t)row * ldc + col] = f2h(v);
                        if ((unsigned)(col - OFF_DT) < 8u)
                            dt32[(size_t)row * 8 + (col - OFF_DT)] = v;
                    } else {
                        ((float*)Cv)[zoff + (size_t)row * ldc + col] = v;
                    }
                }
            }
        }
}

// ---------------------------------------------------------------------------
// split-K=2 reduce + per-row RMS scale (rowSS = atomic-accumulated sum sq)
// ---------------------------------------------------------------------------
__global__ __launch_bounds__(256) void reduce2rms_kernel(const float* __restrict__ p,
                                                         const float* __restrict__ rowSS,
                                                         float* __restrict__ out, int n) {
    int i4 = (blockIdx.x * 256 + threadIdx.x) * 4;
    int m = i4 >> 10;                         // DIM=1024 cols per row
    float scale = rsqrtf(rowSS[m] * (1.f / (float)D_INNER) + 1e-6f);
    float4 a = *(const float4*)&p[i4];
    float4 b = *(const float4*)&p[(size_t)n + i4];
    *(float4*)&out[i4] = make_float4((a.x + b.x) * scale, (a.y + b.y) * scale,
                                     (a.z + b.z) * scale, (a.w + b.w) * scale);
}

// ---------------------------------------------------------------------------
// depthwise causal conv (k=4) + SiLU -> xh (fp16); vectorized u16x8 (G13).
// ---------------------------------------------------------------------------
__global__ __launch_bounds__(256) void conv_silu_kernel(const u16* __restrict__ zxh,
                                                        const float* __restrict__ conv_w,
                                                        const float* __restrict__ conv_b,
                                                        u16* __restrict__ xh) {
    int idx8 = blockIdx.x * 256 + threadIdx.x;   // 0 .. M_ROWS*D_INNER/8-1
    int c0 = (idx8 & 255) * 8;
    int m  = idx8 >> 8;
    int l  = m & (SEQ - 1);

    f32x4 wv[8];
#pragma unroll
    for (int j = 0; j < 8; ++j) wv[j] = *(const f32x4*)&conv_w[(c0 + j) * 4];
    float acc[8];
#pragma unroll
    for (int j = 0; j < 8; ++j) acc[j] = conv_b[c0 + j];
#pragma unroll
    for (int k = 0; k < D_CONV; ++k) {
        int lj = l + k - (D_CONV - 1);
        if (lj >= 0) {
            u16x8 v = *(const u16x8*)&zxh[(size_t)(m + k - (D_CONV - 1)) * NPROJ + OFF_XC + c0];
#pragma unroll
            for (int j = 0; j < 8; ++j)
                acc[j] = fmaf(h2f(v[j]), wv[j][k], acc[j]);
        }
    }
    u16x8 o;
#pragma unroll
    for (int j = 0; j < 8; ++j) o[j] = f2h(acc[j] / (1.f + __expf(-acc[j])));
    *(u16x8*)&xh[(size_t)m * D_INNER + c0] = o;
}

// ---------------------------------------------------------------------------
// PASS 1 (states only): per (b,h,chunk,dq): S_c = (w2*B)^T @ X  -> Sloc (fp16).
// dq==0 block also writes csum[bh][c] = sum of dt over the chunk (SD63).
// Staging vectorized: u16x8 loads (16B), one w2 exp per 8-wide chunk.
// ---------------------------------------------------------------------------
__global__ __launch_bounds__(256) void scan_state_mfma(const u16* __restrict__ zxh,
                                                       const float* __restrict__ dt32,
                                                       const u16* __restrict__ xh,
                                                       const float* __restrict__ dt_bias,
                                                       const float* __restrict__ A_log,
                                                       u16* __restrict__ Sloc,
                                                       float* __restrict__ csum) {
    const int blk = blockIdx.x;                 // 0..1023
    const int dq = blk & 3;
    const int c  = (blk >> 2) & (N_CHUNK - 1);
    const int bh = blk >> 6;
    const int hh = bh & (N_HEADS - 1);
    const int b  = bh >> 3;
    const int t    = threadIdx.x;
    const int wave = t >> 6;
    const int lane = t & 63;
    const int fr   = lane & 15;
    const int quad = lane >> 4;

    __shared__ float SDs[64];
    __shared__ u16 BwT[64 * PADT];
    __shared__ u16 XsT[64 * PADT];

    const int m0   = b * SEQ + c * CHUNK;
    const int xcol = hh * HEAD_DIM + dq * 64;
    const float Ahd = -__expf(A_log[hh]);
    const float dtb = dt_bias[hh];

    if (t < 64) {
        float d = softplus_f(dt32[(size_t)(m0 + t) * 8 + hh] + dtb);
#pragma unroll
        for (int off = 1; off < 64; off <<= 1) {
            float o = __shfl_up(d, off);
            if (lane >= off) d += o;
        }
        SDs[t] = d;
    }
    __syncthreads();
    const float SD63 = SDs[63];
    if (dq == 0 && t == 0) csum[bh * N_CHUNK + c] = SD63;

#pragma unroll
    for (int i = 0; i < 2; ++i) {
        int ch = t + i * 256;                 // 0..511 = 64 rows x 8 chunks
        int r = ch >> 3, n0 = (ch & 7) * 8;
        u16x8 bv8 = *(const u16x8*)&zxh[(size_t)(m0 + r) * NPROJ + OFF_B + n0];
        u16x8 xv8 = *(const u16x8*)&xh[(size_t)(m0 + r) * D_INNER + xcol + n0];
        float w2 = __expf(Ahd * (SD63 - SDs[r]));
#pragma unroll
        for (int j = 0; j < 8; ++j) {
            BwT[(n0 + j) * PADT + r] = f2h(h2f(bv8[j]) * w2);
            XsT[(n0 + j) * PADT + r] = xv8[j];
        }
    }
    __syncthreads();

    const int tm0 = wave * 16;
    f32x4 sa[4];
#pragma unroll
    for (int j = 0; j < 4; ++j) sa[j] = (f32x4)0.f;
    __builtin_amdgcn_s_setprio(1);
#pragma unroll
    for (int kk = 0; kk < 2; ++kk) {
        f16x8 af = *(const f16x8*)&BwT[(tm0 + fr) * PADT + kk * 32 + quad * 8];
#pragma unroll
        for (int j = 0; j < 4; ++j) {
            f16x8 bf = *(const f16x8*)&XsT[(j * 16 + fr) * PADT + kk * 32 + quad * 8];
            sa[j] = __builtin_amdgcn_mfma_f32_16x16x32_f16(af, bf, sa[j], 0, 0, 0);
        }
    }
    __builtin_amdgcn_s_setprio(0);
    size_t sbase = (size_t)(bh * N_CHUNK + c) * STATE_PER_BH;
#pragma unroll
    for (int j = 0; j < 4; ++j)
#pragma unroll
        for (int reg = 0; reg < 4; ++reg) {
            int nn = tm0 + quad * 4 + reg;
            int dd = j * 16 + fr;
            Sloc[sbase + (size_t)nn * HEAD_DIM + dq * 64 + dd] = f2h(sa[j][reg]);
        }
}

// ---------------------------------------------------------------------------
// PASS 2: inter-chunk recurrence in place on fp16 Sloc (u32 = 2 packed fp16).
// ---------------------------------------------------------------------------
__global__ __launch_bounds__(256) void scan_combine2(const float* __restrict__ csum,
                                                     const float* __restrict__ A_log,
                                                     u32* __restrict__ Sl) {
    const int blk = blockIdx.x;               // 0..511
    const int seg = blk & 31;                 // 32 segs x 256 u32 = 8192 u32/chunk
    const int bh  = blk >> 5;
    const int hh  = bh & (N_HEADS - 1);
    const int t   = threadIdx.x;

    __shared__ float PS[N_CHUNK];
    if (t < N_CHUNK) {
        float Ahd = -__expf(A_log[hh]);
        PS[t] = __expf(Ahd * csum[bh * N_CHUNK + t]);
    }
    __syncthreads();

    const int HPC = STATE_PER_BH / 2;         // 8192 u32 per chunk
    size_t base = (size_t)bh * N_CHUNK * HPC + seg * 256 + t;
    u32 Sv[N_CHUNK];
#pragma unroll
    for (int c = 0; c < N_CHUNK; ++c)
        Sv[c] = Sl[base + (size_t)c * HPC];
    float H0 = 0.f, H1 = 0.f;
#pragma unroll
    for (int c = 0; c < N_CHUNK; ++c) {
        Sl[base + (size_t)c * HPC] = ((u32)f2h(H1) << 16) | (u32)f2h(H0);
        float P = PS[c];
        H0 = fmaf(P, H0, h2f((u16)(Sv[c] & 0xffffu)));
        H1 = fmaf(P, H1, h2f((u16)(Sv[c] >> 16)));
    }
}

// ---------------------------------------------------------------------------
// PASS 3 (fused): per (b,h,chunk,dq):
//   G = C@B^T; P = mask*decay*G; Y = P@X + cum*(C@H) + D*x;
//   ybf = fp16(Y * silu(z)); rowSS += per-row sum of squares (atomic).
// 2 barriers: staging (incl Hdn) | G | alias-guard | Ps (same-wave) | PV.
// Ps aliases Bt. 37.2 KB -> 4 blocks/CU.
// ---------------------------------------------------------------------------
__global__ __launch_bounds__(256) void scan_ycorr_mfma(const u16* __restrict__ zxh,
                                                       const float* __restrict__ dt32,
                                                       const u16* __restrict__ xh,
                                                       const float* __restrict__ dt_bias,
                                                       const float* __restrict__ A_log,
                                                       const float* __restrict__ Dp,
                                                       const u16* __restrict__ Hini,
                                                       u16* __restrict__ ybf,
                                                       float* __restrict__ rowSS) {
    const int blk = blockIdx.x;                 // 0..1023
    const int dq = blk & 3;
    const int c  = (blk >> 2) & (N_CHUNK - 1);
    const int bh = blk >> 6;
    const int hh = bh & (N_HEADS - 1);
    const int b  = bh >> 3;
    const int t    = threadIdx.x;
    const int wave = t >> 6;
    const int lane = t & 63;
    const int fr   = lane & 15;
    const int quad = lane >> 4;

    __shared__ float SDs[64];
    __shared__ u16 Ct  [64 * PADT];
    __shared__ u16 BtPs[64 * PADT];             // Bt during G-phase, Ps after
    __shared__ u16 XsT [64 * PADT];
    __shared__ u16 Hdn [64 * PADT];

    const int m0   = b * SEQ + c * CHUNK;
    const int xcol = hh * HEAD_DIM + dq * 64;
    const float Ahd = -__expf(A_log[hh]);
    const float dtb = dt_bias[hh];

    if (t < 64) {
        float d = softplus_f(dt32[(size_t)(m0 + t) * 8 + hh] + dtb);
#pragma unroll
        for (int off = 1; off < 64; off <<= 1) {
            float o = __shfl_up(d, off);
            if (lane >= off) d += o;
        }
        SDs[t] = d;
    }

    // issue H loads first (they return while B/C/X staging proceeds)
    const int hr0 = t >> 3, hn0 = (t & 7) * 8;  // row/col chunks for H and X
    size_t hbase = (size_t)(bh * N_CHUNK + c) * STATE_PER_BH;
    u16x8 hreg0 = *(const u16x8*)&Hini[hbase + (size_t)hr0 * HEAD_DIM + dq * 64 + hn0];
    u16x8 hreg1 = *(const u16x8*)&Hini[hbase + (size_t)(hr0 + 32) * HEAD_DIM + dq * 64 + hn0];

    // B|C staging: 128 contiguous cols (4104..4231), 1024 u16x8 chunks
#pragma unroll
    for (int i = 0; i < 4; ++i) {
        int ch = t + i * 256;                  // 0..1023
        int r = ch >> 4, q = ch & 15;
        u16x8 v = *(const u16x8*)&zxh[(size_t)(m0 + r) * NPROJ + OFF_B + q * 8];
        if (q < 8) *(u16x8*)&BtPs[r * PADT + q * 8] = v;
        else       *(u16x8*)&Ct[r * PADT + (q - 8) * 8] = v;
    }
    // X staging: transposed
#pragma unroll
    for (int i = 0; i < 2; ++i) {
        int ch = t + i * 256;                  // 0..511
        int r = ch >> 3, n0 = (ch & 7) * 8;
        u16x8 xv8 = *(const u16x8*)&xh[(size_t)(m0 + r) * D_INNER + xcol + n0];
#pragma unroll
        for (int j = 0; j < 8; ++j)
            XsT[(n0 + j) * PADT + r] = xv8[j];
    }
    // Hdn staging (transposed) — loads were issued first, minimal stall
#pragma unroll
    for (int j = 0; j < 8; ++j) {
        Hdn[(hn0 + j) * PADT + hr0]      = hreg0[j];
        Hdn[(hn0 + j) * PADT + hr0 + 32] = hreg1[j];
    }
    __syncthreads();

    const int tm0 = wave * 16;

    // G = C@B^T
    f32x4 g[4];
#pragma unroll
    for (int j = 0; j < 4; ++j) g[j] = (f32x4)0.f;
    __builtin_amdgcn_s_setprio(1);
#pragma unroll
    for (int kk = 0; kk < 2; ++kk) {
        f16x8 af = *(const f16x8*)&Ct[(tm0 + fr) * PADT + kk * 32 + quad * 8];
#pragma unroll
        for (int j = 0; j < 4; ++j) {
            f16x8 bf = *(const f16x8*)&BtPs[(j * 16 + fr) * PADT + kk * 32 + quad * 8];
            g[j] = __builtin_amdgcn_mfma_f32_16x16x32_f16(af, bf, g[j], 0, 0, 0);
        }
    }
    __builtin_amdgcn_s_setprio(0);
    __syncthreads();                            // all waves done reading Bt

    // mask + decay -> Ps (into Bt's storage; same-wave rows only)
    {
        int trow = tm0 + quad * 4;
#pragma unroll
        for (int j = 0; j < 4; ++j) {
#pragma unroll
            for (int reg = 0; reg < 4; ++reg) {
                int tt = trow + reg, ss = j * 16 + fr;
                float val = 0.f;
                if (ss <= tt) val = __expf(Ahd * (SDs[tt] - SDs[ss])) * g[j][reg];
                BtPs[tt * PADT + ss] = f2h(val);
            }
        }
    }

    // Y1 = P @ X ; Y2 = C @ H   (no barrier: Ps is same-wave; Hdn/XsT staged)
    f32x4 ya[4], yb[4];
#pragma unroll
    for (int j = 0; j < 4; ++j) { ya[j] = (f32x4)0.f; yb[j] = (f32x4)0.f; }
    __builtin_amdgcn_s_setprio(1);
#pragma unroll
    for (int kk = 0; kk < 2; ++kk) {
        f16x8 afp = *(const f16x8*)&BtPs[(tm0 + fr) * PADT + kk * 32 + quad * 8];
        f16x8 afc = *(const f16x8*)&Ct[(tm0 + fr) * PADT + kk * 32 + quad * 8];
#pragma unroll
        for (int j = 0; j < 4; ++j) {
            f16x8 bx = *(const f16x8*)&XsT[(j * 16 + fr) * PADT + kk * 32 + quad * 8];
            f16x8 bh_ = *(const f16x8*)&Hdn[(j * 16 + fr) * PADT + kk * 32 + quad * 8];
            ya[j] = __builtin_amdgcn_mfma_f32_16x16x32_f16(afp, bx, ya[j], 0, 0, 0);
            yb[j] = __builtin_amdgcn_mfma_f32_16x16x32_f16(afc, bh_, yb[j], 0, 0, 0);
        }
    }
    __builtin_amdgcn_s_setprio(0);

    // epilogue: gate + fp16 store + row sum-of-squares
    const float Dh = Dp[hh];
#pragma unroll
    for (int reg = 0; reg < 4; ++reg) {
        int tt = tm0 + quad * 4 + reg;
        float cum = __expf(Ahd * SDs[tt]);
        size_t rowz = (size_t)(m0 + tt) * NPROJ;
        size_t rowy = (size_t)(m0 + tt) * D_INNER + xcol;
        float ss = 0.f;
#pragma unroll
        for (int j = 0; j < 4; ++j) {
            int dd = j * 16 + fr;
            float xv = h2f(XsT[dd * PADT + tt]);
            float z  = h2f(zxh[rowz + OFF_Z + xcol + dd]);
            float yv = ya[j][reg] + cum * yb[j][reg] + Dh * xv;
            float gated = yv * (z / (1.f + __expf(-z)));
            ybf[rowy + dd] = f2h(gated);
            ss += gated * gated;
        }
        // reduce across the 16 lanes of this quad (fr dimension)
#pragma unroll
        for (int off = 1; off < 16; off <<= 1) ss += __shfl_xor(ss, off);
        if (fr == 0) atomicAdd(&rowSS[m0 + tt], ss);
    }
}

// ---------------------------------------------------------------------------
extern "C" void kernel_launch(void* const* d_in, const int* in_sizes, int n_in,
                              void* d_out, int out_size, void* d_ws, size_t ws_size,
                              hipStream_t stream) {
    const float* x         = (const float*)d_in[0];
    const float* in_proj_w = (const float*)d_in[1];
    const float* conv_w    = (const float*)d_in[2];
    const float* conv_b    = (const float*)d_in[3];
    const float* A_log     = (const float*)d_in[4];
    const float* D_param   = (const float*)d_in[5];
    const float* dt_bias   = (const float*)d_in[6];
    const float* norm_w    = (const float*)d_in[7];
    const float* out_proj_w= (const float*)d_in[8];
    float* out = (float*)d_out;

    // workspace layout (floats):
    //  zx  @0         8,667,136  | zxh(u16, 17.3MB) -> later pbuf (fp32 2x2,097,152)
    //  R1  @8667136   2,166,784  | xh(u16)
    //  R2  @10833920  4,194,304  | lower half: xbf_h(u16) -> ybf(u16)
    //                            | upper half (@+2097152): wobf_h(u16)
    //  ab  @15028224     16,384  | csum(256) + rowSS(2048)
    //  R3  @15044608  4,194,304  | wibf_h(u16) -> Sloc(fp16) | dts fp32 side-buf
    float* ws  = (float*)d_ws;
    float* zx  = ws;
    float* R1  = zx + 8667136;
    float* R2  = R1 + 2166784;
    float* ab  = R2 + 4194304;
    float* R3  = ab + 16384;

    u16*  zxh    = (u16*)zx;                 // fp16 zxBCdt, 2048 x 4232
    u16*  xh     = (u16*)R1;
    u16*  xbf_h  = (u16*)R2;
    u16*  ybf    = (u16*)R2;                 // reuses xbf region after GEMM1
    u16*  wobf_h = (u16*)(R2 + 2097152);     // disjoint from xbf/ybf for all time
    float* csum  = ab;
    float* rowSS = ab + 2048;                // M_ROWS floats, atomic-accumulated
    u16*  wibf_h = (u16*)R3;
    u16*  Sloc   = (u16*)R3;                 // fp16 states; reuses wibf after GEMM1
    float* dts   = R3 + 2166784;             // fp32 dt side-buffer [M_ROWS][8]
    float* pbuf  = zx;                       // GEMM2 partials (2 x 8.4MB), after
                                             //  zxh last read (ycorr)

    // 0) merged casts: x, in_proj_w, out_proj_w*norm_w (+ rowSS zeroing)
    {
        int n0 = M_ROWS * DIM;              // 2,097,152
        int n1 = NPROJ * DIM;               // 4,333,568
        int n2 = DIM * D_INNER;             // 2,097,152
        cast3_kernel<<<(n0 + n1 + n2) / 1024, 256, 0, stream>>>(
            x, xbf_h, n0, in_proj_w, wibf_h, n1, out_proj_w, norm_w, wobf_h, n2,
            rowSS);
    }

    // 1) zxBCdt = x @ in_proj_w^T  (2048 x 4232, K=1024), BN=128, fp16 out
    gemm_mfma1<128, true><<<dim3(NPROJ_PAD / 128, M_ROWS / 128, 1), 256, 0, stream>>>(
        xbf_h, wibf_h, zxh, dts, DIM, NPROJ, NPROJ, NPROJ, 0);

    // 2) conv + silu -> xh (fp16), vectorized u16x8
    conv_silu_kernel<<<(M_ROWS * D_INNER) / (256 * 8), 256, 0, stream>>>(
        zxh, conv_w, conv_b, xh);

    // 3) SSD chunked scan (fp16 states)
    scan_state_mfma<<<BATCH * N_HEADS * N_CHUNK * 4, 256, 0, stream>>>(
        zxh, dts, xh, dt_bias, A_log, Sloc, csum);
    scan_combine2<<<BATCH * N_HEADS * 32, 256, 0, stream>>>(
        csum, A_log, (u32*)Sloc);
    scan_ycorr_mfma<<<BATCH * N_HEADS * N_CHUNK * 4, 256, 0, stream>>>(
        zxh, dts, xh, dt_bias, A_log, D_param, Sloc, ybf, rowSS);

    // 4) out_pre = y_gated @ (W*nw)^T  (2048 x 1024, K=2048), BN=64, split-K=2
    gemm_mfma1<64, false><<<dim3(DIM / 64, M_ROWS / 128, 2), 256, 0, stream>>>(
        ybf, wobf_h, pbuf, nullptr, D_INNER, DIM, DIM, DIM,
        (size_t)M_ROWS * DIM);

    // 5) reduce partials + apply per-row RMS scale -> out
    reduce2rms_kernel<<<(M_ROWS * DIM) / 1024, 256, 0, stream>>>(
        pbuf, rowSS, out, M_ROWS * DIM);
}